// Round 2
// baseline (833.241 us; speedup 1.0000x reference)
//
#include <hip/hip_runtime.h>

#define B_   128
#define S_   1024
#define NT_  258
#define TG_  256
#define LN2f 0.69314718056f
#define RSTR 264            // state row stride in bf16 elements (132 dwords: reads 8/bank optimal, writes 2-way)
#define BUF  (16*RSTR)      // elems per state buffer

typedef __attribute__((ext_vector_type(8))) short bf8_t;   // 8 bf16 (4 VGPR) MFMA A/B frag
typedef __attribute__((ext_vector_type(4))) float f4_t;    // MFMA C/D frag

__device__ __forceinline__ unsigned short f2bf(float f) {
  unsigned u = __float_as_uint(f);
  u += 0x7fffu + ((u >> 16) & 1u);          // RTNE
  return (unsigned short)(u >> 16);
}
__device__ __forceinline__ float bf2f(unsigned short s) {
  return __uint_as_float(((unsigned)s) << 16);
}
__device__ __forceinline__ unsigned pk_bf16(float lo, float hi) {
  unsigned d;
  asm("v_cvt_pk_bf16_f32 %0, %1, %2" : "=v"(d) : "v"(lo), "v"(hi));
  return d;
}

// ---------------------------------------------------------------------------
// Scan kernel: 8 blocks x 256 threads (4 waves, 1/SIMD). Block owns 16 batches.
// State a[b][k] = exp(la[b][k] - c_b) in LDS bf16, double-buffered, row stride
// RSTR=264. Per step: C = a @ expT (MFMA, wave owns 64 cols = 4 tiles),
// a' = exp(em) * C (masked), power-of-2 rescale every 8 steps via earr/esv.
// ---------------------------------------------------------------------------
__global__ __launch_bounds__(256, 1) void crf_scan(
    const float* __restrict__ logits, const float* __restrict__ trans,
    const int* __restrict__ y, float* __restrict__ ws)
{
  __shared__ __align__(16) unsigned short aL[2*BUF];
  __shared__ __align__(16) int   earr[16];
  __shared__ float esumL[16];
  __shared__ float refL[16];

  const int tid = threadIdx.x;
  const int w  = tid >> 6;        // wave 0..3
  const int l  = tid & 63;
  const int bq = blockIdx.x * 16;
  const int lg = l >> 4;          // lane group 0..3
  const int lc = l & 15;

  // ---- B preload (expT cols 64w+16ti+lc), step-invariant, 128 VGPRs
  bf8_t Bf[4][8];
#pragma unroll
  for (int ti = 0; ti < 4; ++ti) {
    const int n = 64*w + 16*ti + lc;
#pragma unroll
    for (int kk = 0; kk < 8; ++kk) {
      bf8_t bv;
#pragma unroll
      for (int e = 0; e < 8; ++e) {
        const int k = kk*32 + lg*8 + e;
        bv[e] = (short)f2bf(__expf(trans[k*NT_ + n]));
      }
      Bf[ti][kk] = bv;
    }
  }

  // ---- address bases (element units; kk/ti offsets fold into imm offsets)
  const int idxA0 = lc*RSTR + lg*8;            // A-frag: row=lc, k=kk*32+lg*8+e
  int idxW_r[4], embase_r[4], ybase[4];
#pragma unroll
  for (int r = 0; r < 4; ++r) {
    const int b = 4*lg + r;                    // C-frag row = (lane>>4)*4 + reg
    idxW_r[r]   = b*RSTR + 64*w + lc;          // C-frag col = lane&15 (+16*ti)
    embase_r[r] = (bq + b)*(S_*256) + 64*w + lc;
    ybase[r]    = (bq + b)*S_;
  }

  // ---- init t=0: la0 = logits[:,0,:] + T[START,:]; a0 = exp(la0 - la0[b][0])
  {
    const int bi = tid >> 4, cb = (tid & 15) * 16;
    if (tid < 16) {
      refL[tid]  = logits[(size_t)(bq + tid)*(S_*256)] + trans[TG_*NT_];
      esumL[tid] = 0.f;
    }
    __syncthreads();
    const float ref = refL[bi];
#pragma unroll
    for (int c4 = 0; c4 < 4; ++c4) {
      const int j = cb + 4*c4;
      const float4 em = *(const float4*)&logits[(size_t)(bq + bi)*(S_*256) + j];
      const float4 ts = *(const float4*)&trans[TG_*NT_ + j];
      const unsigned d0 = pk_bf16(__expf(em.x + ts.x - ref), __expf(em.y + ts.y - ref));
      const unsigned d1 = pk_bf16(__expf(em.z + ts.z - ref), __expf(em.w + ts.w - ref));
      aL[bi*RSTR + j + 0] = (unsigned short)d0;
      aL[bi*RSTR + j + 1] = (unsigned short)(d0 >> 16);
      aL[bi*RSTR + j + 2] = (unsigned short)d1;
      aL[bi*RSTR + j + 3] = (unsigned short)(d1 >> 16);
    }
  }

  // ---- prefetch em/y for t=1 (A set) and t=2 (B set)
  float emA[4][4], emB[4][4];
  int yA[4], yB[4];
#pragma unroll
  for (int r = 0; r < 4; ++r) {
    yA[r] = y[ybase[r] + 1];
    yB[r] = y[ybase[r] + 2];
#pragma unroll
    for (int ti = 0; ti < 4; ++ti) {
      emA[ti][r] = logits[embase_r[r] + 16*ti + 1*256];
      emB[ti][r] = logits[embase_r[r] + 16*ti + 2*256];
    }
  }
  float esv[4] = {0.f, 0.f, 0.f, 0.f};   // per-batch exponent sums (w0,lc0 lanes)

  __syncthreads();

#define SCAN_STEP(T_, CURE_, NXTE_, EMV_, YV_) do {                           \
  bf8_t Af_[8];                                                               \
  _Pragma("unroll") for (int kk = 0; kk < 8; ++kk)                            \
    Af_[kk] = *(const bf8_t*)&aL[(CURE_) + idxA0 + 32*kk];                    \
  float F_[4][4]; int m_[4];                                                  \
  _Pragma("unroll") for (int r = 0; r < 4; ++r) {                             \
    m_[r] = YV_[r];                                                           \
    _Pragma("unroll") for (int ti = 0; ti < 4; ++ti)                          \
      F_[ti][r] = __expf(EMV_[ti][r]); }                                      \
  const int tp_ = ((T_)+2 < S_) ? ((T_)+2) : (S_-1);                          \
  _Pragma("unroll") for (int r = 0; r < 4; ++r) {                             \
    YV_[r] = y[ybase[r] + tp_];                                               \
    _Pragma("unroll") for (int ti = 0; ti < 4; ++ti)                          \
      EMV_[ti][r] = logits[embase_r[r] + 16*ti + tp_*256]; }                  \
  f4_t c_[4] = {{0,0,0,0},{0,0,0,0},{0,0,0,0},{0,0,0,0}};                     \
  _Pragma("unroll") for (int kk = 0; kk < 8; ++kk)                            \
    _Pragma("unroll") for (int ti = 0; ti < 4; ++ti)                          \
      c_[ti] = __builtin_amdgcn_mfma_f32_16x16x32_bf16(Af_[kk], Bf[ti][kk], c_[ti], 0, 0, 0); \
  float v_[4][4];                                                             \
  _Pragma("unroll") for (int ti = 0; ti < 4; ++ti)                            \
    _Pragma("unroll") for (int r = 0; r < 4; ++r)                             \
      v_[ti][r] = F_[ti][r]*c_[ti][r];                                        \
  if (((T_) & 7) == 0) {                   /* apply rescale published at T-1 */ \
    const int4 er_ = *(const int4*)&earr[lg*4];                               \
    _Pragma("unroll") for (int ti = 0; ti < 4; ++ti) {                        \
      v_[ti][0] = ldexpf(v_[ti][0], -er_.x);                                  \
      v_[ti][1] = ldexpf(v_[ti][1], -er_.y);                                  \
      v_[ti][2] = ldexpf(v_[ti][2], -er_.z);                                  \
      v_[ti][3] = ldexpf(v_[ti][3], -er_.w); }                                \
    if (w == 0 && lc == 0) {                                                  \
      if (m_[0] >= 0) esv[0] += (float)er_.x;                                 \
      if (m_[1] >= 0) esv[1] += (float)er_.y;                                 \
      if (m_[2] >= 0) esv[2] += (float)er_.z;                                 \
      if (m_[3] >= 0) esv[3] += (float)er_.w; } }                             \
  _Pragma("unroll") for (int r = 0; r < 4; ++r) {                             \
    if (m_[r] >= 0) {                       /* masked rows stay frozen */     \
      const unsigned d0_ = pk_bf16(v_[0][r], v_[1][r]);                       \
      const unsigned d1_ = pk_bf16(v_[2][r], v_[3][r]);                       \
      aL[(NXTE_) + idxW_r[r] +  0] = (unsigned short)d0_;                     \
      aL[(NXTE_) + idxW_r[r] + 16] = (unsigned short)(d0_ >> 16);             \
      aL[(NXTE_) + idxW_r[r] + 32] = (unsigned short)d1_;                     \
      aL[(NXTE_) + idxW_r[r] + 48] = (unsigned short)(d1_ >> 16); } }         \
  if (((T_) & 7) == 7 && w == 0 && lc == 0) {  /* publish exponent of a[b][0] */ \
    _Pragma("unroll") for (int r = 0; r < 4; ++r)                             \
      earr[4*lg + r] = (int)((__float_as_uint(v_[0][r]) >> 23) & 255) - 127; } \
  asm volatile("s_waitcnt lgkmcnt(0)" ::: "memory");  /* LDS drain only —   */ \
  __builtin_amdgcn_s_barrier();                       /* keep global        */ \
  asm volatile("" ::: "memory");                      /* prefetch in flight */ \
} while (0)

  SCAN_STEP(1, 0, BUF, emA, yA);
#pragma unroll 1
  for (int tt = 2; tt < S_; tt += 2) {
    SCAN_STEP(tt,   BUF, 0, emB, yB);
    SCAN_STEP(tt+1, 0, BUF, emA, yA);
  }
#undef SCAN_STEP

  // ---- finalize: log_z[b] = log( sum_j a[b][j]*exp(T[j,END]) ) + esum*ln2 + ref
  if (w == 0 && lc == 0) {
#pragma unroll
    for (int r = 0; r < 4; ++r) esumL[4*lg + r] = esv[r];
  }
  __syncthreads();
  {
    const int bi = tid >> 4, j0 = (tid & 15) * 16;
    float p = 0.f;
#pragma unroll
    for (int c4 = 0; c4 < 4; ++c4) {
      const int j = j0 + 4*c4;
#pragma unroll
      for (int e = 0; e < 4; ++e) {
        const int k = j + e;
        p += bf2f(aL[BUF + bi*RSTR + k]) * __expf(trans[k*NT_ + 257]);
      }
    }
#pragma unroll
    for (int o = 8; o; o >>= 1) p += __shfl_xor(p, o, 16);
    if ((tid & 15) == 0)
      ws[128 + bq + bi] = __logf(p) + esumL[bi]*LN2f + refL[bi];
  }
}

// ---------------------------------------------------------------------------
// llh (gold-path score) + lengths: 128 blocks x 256 threads, t-parallel.
// ---------------------------------------------------------------------------
__global__ void crf_llh(const float* __restrict__ logits, const float* __restrict__ trans,
                        const int* __restrict__ y, float* __restrict__ ws)
{
  const int b = blockIdx.x, tid = threadIdx.x;
  const int yb = b * S_;
  float part = 0.f; int cnt = 0;
  for (int t = tid; t < S_; t += 256) {
    const int yt = y[yb + t];
    const bool m = (yt >= 0);
    if (m) ++cnt;
    if (t == 0) {
      const int tag0 = m ? yt : 0;
      part += trans[TG_*NT_ + tag0];                       // T[START, y0]
      if (m) part += logits[(size_t)yb * 256 + tag0];
    } else if (m) {
      const int yp = y[yb + t - 1];                        // mask monotone => valid
      part += logits[((size_t)(yb + t)) * 256 + yt] + trans[yp*NT_ + yt];
    }
    if (m && (t + 1 == S_ || y[yb + t + 1] < 0))
      part += trans[yt*NT_ + 257];                         // T[last, END]
  }
#pragma unroll
  for (int o = 32; o; o >>= 1) { part += __shfl_xor(part, o); cnt += __shfl_xor(cnt, o); }
  __shared__ float sp[4]; __shared__ int sc[4];
  if ((tid & 63) == 0) { sp[tid >> 6] = part; sc[tid >> 6] = cnt; }
  __syncthreads();
  if (tid == 0) {
    ws[b]       = sp[0] + sp[1] + sp[2] + sp[3];
    ws[256 + b] = (float)(sc[0] + sc[1] + sc[2] + sc[3]);
  }
}

// ---------------------------------------------------------------------------
// loss = mean_b( -(llh - log_z)/len )
// ---------------------------------------------------------------------------
__global__ void crf_fin(const float* __restrict__ ws, float* __restrict__ out)
{
  const int i = threadIdx.x;  // 128
  float v = -(ws[i] - ws[128 + i]) / ws[256 + i];
#pragma unroll
  for (int o = 32; o; o >>= 1) v += __shfl_xor(v, o);
  __shared__ float s2[2];
  if ((i & 63) == 0) s2[i >> 6] = v;
  __syncthreads();
  if (i == 0) out[0] = (s2[0] + s2[1]) * (1.0f / 128.0f);
}

extern "C" void kernel_launch(void* const* d_in, const int* in_sizes, int n_in,
                              void* d_out, int out_size, void* d_ws, size_t ws_size,
                              hipStream_t stream)
{
  const float* logits = (const float*)d_in[0];
  const float* trans  = (const float*)d_in[1];
  const int*   y      = (const int*)d_in[2];
  float* ws  = (float*)d_ws;   // [0,128) llh | [128,256) log_z | [256,384) len
  float* out = (float*)d_out;

  hipLaunchKernelGGL(crf_llh,  dim3(128), dim3(256), 0, stream, logits, trans, y, ws);
  hipLaunchKernelGGL(crf_scan, dim3(8),   dim3(256), 0, stream, logits, trans, y, ws);
  hipLaunchKernelGGL(crf_fin,  dim3(1),   dim3(128), 0, stream, ws, out);
}

// Round 3
// 683.872 us; speedup vs baseline: 1.2184x; 1.2184x over previous
//
#include <hip/hip_runtime.h>

#define B_   128
#define S_   1024
#define NT_  258
#define TG_  256
#define LN2f 0.69314718056f
#define RSTR 264            // state row stride in bf16 elems (132 dwords: b128 reads at 8/bank floor, b32 writes 2/bank)
#define BUF  (16*RSTR)      // elems per state buffer

typedef __attribute__((ext_vector_type(8))) short bf8_t;   // 8 bf16 (4 VGPR) MFMA A/B frag
typedef __attribute__((ext_vector_type(4))) float f4_t;    // MFMA C/D frag

__device__ __forceinline__ unsigned short f2bf(float f) {
  unsigned u = __float_as_uint(f);
  u += 0x7fffu + ((u >> 16) & 1u);          // RTNE
  return (unsigned short)(u >> 16);
}
__device__ __forceinline__ float bf2f(unsigned short s) {
  return __uint_as_float(((unsigned)s) << 16);
}
__device__ __forceinline__ unsigned pk_bf16(float lo, float hi) {
  unsigned d;
  asm("v_cvt_pk_bf16_f32 %0, %1, %2" : "=v"(d) : "v"(lo), "v"(hi));
  return d;
}

// ---------------------------------------------------------------------------
// Scan: 8 blocks x 512 threads (8 waves, 2/SIMD for latency hiding).
// Block owns 16 batches. State a[b][k]=exp(la-c_b) in LDS bf16, double-buffered.
// Wave w owns 32 INTERLEAVED columns: tile ti in {0,1}, lane lc -> global col
// 32w + 2*lc + ti, so each lane holds 2 adjacent cols -> one packed
// ds_write_b32 per row (conflict-free). Reads unchanged (row-major, RSTR=264).
// ---------------------------------------------------------------------------
__global__ __launch_bounds__(512, 2) void crf_scan(
    const float* __restrict__ logits, const float* __restrict__ trans,
    const int* __restrict__ y, float* __restrict__ ws)
{
  __shared__ __align__(16) unsigned short aL[2*BUF];
  __shared__ __align__(16) int   earr[16];
  __shared__ float esumL[16];
  __shared__ float refL[16];

  const int tid = threadIdx.x;
  const int w  = tid >> 6;        // wave 0..7
  const int l  = tid & 63;
  const int bq = blockIdx.x * 16;
  const int lg = l >> 4;          // lane group 0..3
  const int lc = l & 15;

  // ---- B preload (expT cols 32w+2lc+ti), step-invariant, 64 VGPRs
  bf8_t Bf0[8], Bf1[8];
#pragma unroll
  for (int kk = 0; kk < 8; ++kk) {
    bf8_t b0, b1;
    const int n = 32*w + 2*lc;
#pragma unroll
    for (int e = 0; e < 8; ++e) {
      const int k = kk*32 + lg*8 + e;
      b0[e] = (short)f2bf(__expf(trans[k*NT_ + n]));
      b1[e] = (short)f2bf(__expf(trans[k*NT_ + n + 1]));
    }
    Bf0[kk] = b0; Bf1[kk] = b1;
  }

  // ---- address bases (element units)
  const int idxA0 = lc*RSTR + lg*8;            // A-frag: row=lc, k=kk*32+lg*8+e
  int idxW_r[4], embase_r[4], ybase[4];
#pragma unroll
  for (int r = 0; r < 4; ++r) {
    const int b = 4*lg + r;                    // C-frag row = (lane>>4)*4 + reg
    idxW_r[r]   = b*RSTR + 32*w + 2*lc;        // packed pair (col, col+1)
    embase_r[r] = (bq + b)*(S_*256) + 32*w + 2*lc;
    ybase[r]    = (bq + b)*S_;
  }

  // ---- init t=0: la0 = logits[:,0,:] + T[START,:]; a0 = exp(la0 - la0[b][0])
  {
    if (tid < 16) {
      refL[tid]  = logits[(size_t)(bq + tid)*(S_*256)] + trans[TG_*NT_];
      esumL[tid] = 0.f;
    }
    __syncthreads();
    const int bi = tid >> 5;            // 16 rows, 32 threads each
    const int cb = (tid & 31) * 8;      // 8 cols per thread
    const float ref = refL[bi];
    uint2 dd;
    {
      const float4 em = *(const float4*)&logits[(size_t)(bq + bi)*(S_*256) + cb];
      const float4 ts = *(const float4*)&trans[TG_*NT_ + cb];
      dd.x = pk_bf16(__expf(em.x + ts.x - ref), __expf(em.y + ts.y - ref));
      dd.y = pk_bf16(__expf(em.z + ts.z - ref), __expf(em.w + ts.w - ref));
    }
    *(uint2*)&aL[bi*RSTR + cb] = dd;
    {
      const float4 em = *(const float4*)&logits[(size_t)(bq + bi)*(S_*256) + cb + 4];
      const float4 ts = *(const float4*)&trans[TG_*NT_ + cb + 4];
      dd.x = pk_bf16(__expf(em.x + ts.x - ref), __expf(em.y + ts.y - ref));
      dd.y = pk_bf16(__expf(em.z + ts.z - ref), __expf(em.w + ts.w - ref));
    }
    *(uint2*)&aL[bi*RSTR + cb + 4] = dd;
  }

  // ---- prefetch em/y for t=1 (A set) and t=2 (B set)
  float2 emA[4], emB[4];
  int yA[4], yB[4];
#pragma unroll
  for (int r = 0; r < 4; ++r) {
    yA[r] = y[ybase[r] + 1];
    yB[r] = y[ybase[r] + 2];
    emA[r] = *(const float2*)&logits[embase_r[r] + 1*256];
    emB[r] = *(const float2*)&logits[embase_r[r] + 2*256];
  }
  float esv[4] = {0.f, 0.f, 0.f, 0.f};   // per-batch exponent sums (w0,lc0 lanes)

  __syncthreads();

#define SCAN_STEP(T_, CURE_, NXTE_, EMV_, YV_) do {                           \
  bf8_t Af_[8];                                                               \
  _Pragma("unroll") for (int kk = 0; kk < 8; ++kk)                            \
    Af_[kk] = *(const bf8_t*)&aL[(CURE_) + idxA0 + 32*kk];                    \
  float F0_[4], F1_[4]; int m_[4];                                            \
  _Pragma("unroll") for (int r = 0; r < 4; ++r) {                             \
    m_[r] = YV_[r];                                                           \
    F0_[r] = __expf(EMV_[r].x); F1_[r] = __expf(EMV_[r].y); }                 \
  const int tp_ = ((T_)+2 < S_) ? ((T_)+2) : (S_-1);                          \
  _Pragma("unroll") for (int r = 0; r < 4; ++r) {                             \
    YV_[r] = y[ybase[r] + tp_];                                               \
    EMV_[r] = *(const float2*)&logits[embase_r[r] + tp_*256]; }               \
  f4_t c0_ = {0.f,0.f,0.f,0.f}, c1_ = {0.f,0.f,0.f,0.f};                      \
  _Pragma("unroll") for (int kk = 0; kk < 8; ++kk) {                          \
    c0_ = __builtin_amdgcn_mfma_f32_16x16x32_bf16(Af_[kk], Bf0[kk], c0_, 0, 0, 0); \
    c1_ = __builtin_amdgcn_mfma_f32_16x16x32_bf16(Af_[kk], Bf1[kk], c1_, 0, 0, 0); } \
  float v0_[4], v1_[4];                                                       \
  _Pragma("unroll") for (int r = 0; r < 4; ++r) {                             \
    v0_[r] = F0_[r]*c0_[r]; v1_[r] = F1_[r]*c1_[r]; }                         \
  if (((T_) & 7) == 0) {                   /* apply rescale published at T-1 */ \
    const int4 er_ = *(const int4*)&earr[lg*4];                               \
    v0_[0] = ldexpf(v0_[0], -er_.x); v1_[0] = ldexpf(v1_[0], -er_.x);         \
    v0_[1] = ldexpf(v0_[1], -er_.y); v1_[1] = ldexpf(v1_[1], -er_.y);         \
    v0_[2] = ldexpf(v0_[2], -er_.z); v1_[2] = ldexpf(v1_[2], -er_.z);         \
    v0_[3] = ldexpf(v0_[3], -er_.w); v1_[3] = ldexpf(v1_[3], -er_.w);         \
    if (w == 0 && lc == 0) {                                                  \
      if (m_[0] >= 0) esv[0] += (float)er_.x;                                 \
      if (m_[1] >= 0) esv[1] += (float)er_.y;                                 \
      if (m_[2] >= 0) esv[2] += (float)er_.z;                                 \
      if (m_[3] >= 0) esv[3] += (float)er_.w; } }                             \
  _Pragma("unroll") for (int r = 0; r < 4; ++r) {                             \
    unsigned d_ = pk_bf16(v0_[r], v1_[r]);                                    \
    const unsigned old_ = *(const unsigned*)&aL[(CURE_) + idxW_r[r]];         \
    if (m_[r] < 0) d_ = old_;              /* frozen rows carry exact value */ \
    *(unsigned*)&aL[(NXTE_) + idxW_r[r]] = d_; }                              \
  if (((T_) & 7) == 7 && w == 0 && lc == 0) {  /* publish exponent of a[b][0] */ \
    _Pragma("unroll") for (int r = 0; r < 4; ++r)                             \
      earr[4*lg + r] = (int)((__float_as_uint(v0_[r]) >> 23) & 255) - 127; }  \
  asm volatile("s_waitcnt lgkmcnt(0)" ::: "memory");  /* LDS drain only —   */ \
  __builtin_amdgcn_s_barrier();                       /* keep global        */ \
  asm volatile("" ::: "memory");                      /* prefetch in flight */ \
} while (0)

  SCAN_STEP(1, 0, BUF, emA, yA);
#pragma unroll 1
  for (int tt = 2; tt < S_; tt += 2) {
    SCAN_STEP(tt,   BUF, 0, emB, yB);
    SCAN_STEP(tt+1, 0, BUF, emA, yA);
  }
#undef SCAN_STEP

  // ---- finalize: log_z[b] = log( sum_j a[b][j]*exp(T[j,END]) ) + esum*ln2 + ref
  if (w == 0 && lc == 0) {
#pragma unroll
    for (int r = 0; r < 4; ++r) esumL[4*lg + r] = esv[r];
  }
  __syncthreads();
  {
    const int bi = tid >> 5, j0 = (tid & 31) * 8;
    float p = 0.f;
#pragma unroll
    for (int e = 0; e < 8; ++e) {
      const int k = j0 + e;
      p += bf2f(aL[BUF + bi*RSTR + k]) * __expf(trans[k*NT_ + 257]);
    }
#pragma unroll
    for (int o = 16; o; o >>= 1) p += __shfl_xor(p, o, 32);
    if ((tid & 31) == 0)
      ws[128 + bq + bi] = __logf(p) + esumL[bi]*LN2f + refL[bi];
  }
}

// ---------------------------------------------------------------------------
// llh (gold-path score) + lengths: 128 blocks x 256 threads, t-parallel.
// ---------------------------------------------------------------------------
__global__ void crf_llh(const float* __restrict__ logits, const float* __restrict__ trans,
                        const int* __restrict__ y, float* __restrict__ ws)
{
  const int b = blockIdx.x, tid = threadIdx.x;
  const int yb = b * S_;
  float part = 0.f; int cnt = 0;
  for (int t = tid; t < S_; t += 256) {
    const int yt = y[yb + t];
    const bool m = (yt >= 0);
    if (m) ++cnt;
    if (t == 0) {
      const int tag0 = m ? yt : 0;
      part += trans[TG_*NT_ + tag0];                       // T[START, y0]
      if (m) part += logits[(size_t)yb * 256 + tag0];
    } else if (m) {
      const int yp = y[yb + t - 1];                        // mask monotone => valid
      part += logits[((size_t)(yb + t)) * 256 + yt] + trans[yp*NT_ + yt];
    }
    if (m && (t + 1 == S_ || y[yb + t + 1] < 0))
      part += trans[yt*NT_ + 257];                         // T[last, END]
  }
#pragma unroll
  for (int o = 32; o; o >>= 1) { part += __shfl_xor(part, o); cnt += __shfl_xor(cnt, o); }
  __shared__ float sp[4]; __shared__ int sc[4];
  if ((tid & 63) == 0) { sp[tid >> 6] = part; sc[tid >> 6] = cnt; }
  __syncthreads();
  if (tid == 0) {
    ws[b]       = sp[0] + sp[1] + sp[2] + sp[3];
    ws[256 + b] = (float)(sc[0] + sc[1] + sc[2] + sc[3]);
  }
}

// ---------------------------------------------------------------------------
// loss = mean_b( -(llh - log_z)/len )
// ---------------------------------------------------------------------------
__global__ void crf_fin(const float* __restrict__ ws, float* __restrict__ out)
{
  const int i = threadIdx.x;  // 128
  float v = -(ws[i] - ws[128 + i]) / ws[256 + i];
#pragma unroll
  for (int o = 32; o; o >>= 1) v += __shfl_xor(v, o);
  __shared__ float s2[2];
  if ((i & 63) == 0) s2[i >> 6] = v;
  __syncthreads();
  if (i == 0) out[0] = (s2[0] + s2[1]) * (1.0f / 128.0f);
}

extern "C" void kernel_launch(void* const* d_in, const int* in_sizes, int n_in,
                              void* d_out, int out_size, void* d_ws, size_t ws_size,
                              hipStream_t stream)
{
  const float* logits = (const float*)d_in[0];
  const float* trans  = (const float*)d_in[1];
  const int*   y      = (const int*)d_in[2];
  float* ws  = (float*)d_ws;   // [0,128) llh | [128,256) log_z | [256,384) len
  float* out = (float*)d_out;

  hipLaunchKernelGGL(crf_llh,  dim3(128), dim3(256), 0, stream, logits, trans, y, ws);
  hipLaunchKernelGGL(crf_scan, dim3(8),   dim3(512), 0, stream, logits, trans, y, ws);
  hipLaunchKernelGGL(crf_fin,  dim3(1),   dim3(128), 0, stream, ws, out);
}